// Round 5
// baseline (762.084 us; speedup 1.0000x reference)
//
#include <hip/hip_runtime.h>

#define HOUT 15
#define WOUT 15
// input  (32, 32, 32, 32, 16)  fp32
// ncv    (32, 32, 15, 15, 16)  fp32
// w      (3, 3, 32, 4, 4, 32)  fp32   strides: kl 16384, n 512, xd 32, m 1
// out    (32, 32, 15, 15, 16)  fp32 = 3,686,400 floats

typedef float v2 __attribute__((ext_vector_type(2)));

// ---------------- pass 0: transpose w -> wT[n][kl][m][16] ------------------
// 9216 rows of 16. Reads coalesced over m (stride-1), writes fully contiguous.
__global__ __launch_bounds__(256) void w_transpose(
    const float* __restrict__ wt, float* __restrict__ wT)
{
    const int t = blockIdx.x * 256 + threadIdx.x;   // 0..9215
    const int n  = t / 288;
    const int r  = t % 288;
    const int kl = r >> 5;
    const int m  = r & 31;

    const float* src = wt + kl * 16384 + n * 512 + m;
    float v[16];
#pragma unroll
    for (int xd = 0; xd < 16; ++xd) v[xd] = src[xd * 32];

    float* dst = wT + (size_t)t * 16;
#pragma unroll
    for (int j = 0; j < 4; ++j) {
        float4 o = {v[4 * j], v[4 * j + 1], v[4 * j + 2], v[4 * j + 3]};
        *(float4*)(dst + 4 * j) = o;
    }
}

// ---------------- pass 1: partial accumulation over half the n range -------
// One 32-lane group per output position (b,h,w); lane = m. 8 groups / block.
// blockIdx.y = n-split. No LDS, no barriers: w read directly from wT rows
// (4x global_load_dwordx4, L1/L2-resident). Partials atomicAdd into out.
__global__ __launch_bounds__(256, 2) void caps_part(
    const float* __restrict__ input,
    const float* __restrict__ ncv,
    const float* __restrict__ wT,
    float* __restrict__ out)
{
    const int tid  = threadIdx.x;
    const int grp  = tid >> 5;     // 0..7
    const int lane = tid & 31;     // m

    const int pos = blockIdx.x * 8 + grp;
    const int b   = pos / (HOUT * WOUT);
    const int hw  = pos % (HOUT * WOUT);
    const int h   = hw / WOUT;
    const int wo  = hw % WOUT;

    const int n0 = blockIdx.y * 16;

    // ncv[b, m=lane, h, wo, 0..15] packed as 8 x float2
    const float* ncv_p = ncv + ((((size_t)b * 32 + lane) * HOUT + h) * WOUT + wo) * 16;
    v2 cv2[8];
#pragma unroll
    for (int j = 0; j < 8; ++j) cv2[j] = *(const v2*)(ncv_p + j * 2);

    v2 acc2[8];
#pragma unroll
    for (int j = 0; j < 8; ++j) acc2[j] = (v2){0.0f, 0.0f};

    const int h0 = h * 2, w0 = wo * 2;

    for (int i = 0; i < 16; ++i) {
        const int n = n0 + i;
        const float* ipn = input + ((((size_t)b * 32 + n) * 32 + h0) * 32 + w0) * 16;
        const float* wn  = wT + ((size_t)n * 288 + lane) * 16;

#pragma unroll
        for (int k = 0; k < 3; ++k) {
#pragma unroll
            for (int l = 0; l < 3; ++l) {
                const int kl = k * 3 + l;
                // inp[b, n, 2h+k, 2w+l, 0..15] -- group-uniform broadcast
                const float* ip = ipn + (k * 32 + l) * 16;
                float av[16];
#pragma unroll
                for (int j = 0; j < 16; j += 4) {
                    float4 t = *(const float4*)(ip + j);
                    av[j] = t.x; av[j + 1] = t.y; av[j + 2] = t.z; av[j + 3] = t.w;
                }

                // wT row for (n,kl,m): 16 contiguous floats, lane-coalesced
                const float* wr = wn + kl * 512;   // 32 rows * 16 floats
                float4 wv[4];
#pragma unroll
                for (int x = 0; x < 4; ++x) wv[x] = *(const float4*)(wr + 4 * x);

                // u[a,d] = sum_x av[a,x]*w[x,d,m]; d-pairs -> v_pk_fma_f32
                v2 u2[8];
#pragma unroll
                for (int j = 0; j < 8; ++j) u2[j] = (v2){0.0f, 0.0f};
#pragma unroll
                for (int x = 0; x < 4; ++x) {
                    v2 wlo = {wv[x].x, wv[x].y};
                    v2 whi = {wv[x].z, wv[x].w};
#pragma unroll
                    for (int a = 0; a < 4; ++a) {
                        v2 sp = {av[a * 4 + x], av[a * 4 + x]};
                        u2[a * 2 + 0] = __builtin_elementwise_fma(sp, wlo, u2[a * 2 + 0]);
                        u2[a * 2 + 1] = __builtin_elementwise_fma(sp, whi, u2[a * 2 + 1]);
                    }
                }

                // logit = 0.25 * <u, cv>
                v2 d0 = {0.f, 0.f}, d1 = {0.f, 0.f};
#pragma unroll
                for (int j = 0; j < 4; ++j) {
                    d0 = __builtin_elementwise_fma(u2[j],     cv2[j],     d0);
                    d1 = __builtin_elementwise_fma(u2[j + 4], cv2[j + 4], d1);
                }
                v2 dd = d0 + d1;
                float logit = (dd.x + dd.y) * 0.25f;

                // softmax over m (32 lanes); no max-subtract (|logit| << 80)
                float e = __expf(logit);
                float sum = e;
#pragma unroll
                for (int o = 16; o > 0; o >>= 1)
                    sum += __shfl_xor(sum, o, 32);
                float p = e * __builtin_amdgcn_rcpf(sum);
                v2 p2 = {p, p};

#pragma unroll
                for (int j = 0; j < 8; ++j)
                    acc2[j] = __builtin_elementwise_fma(p2, u2[j], acc2[j]);
            }
        }
    }

    // accumulate partial into out[b][m][h][w][16] (zeroed by host memset)
    float* op = out + ((((size_t)b * 32 + lane) * HOUT + h) * WOUT + wo) * 16;
#pragma unroll
    for (int j = 0; j < 8; ++j) {
        atomicAdd(op + 2 * j,     acc2[j].x);
        atomicAdd(op + 2 * j + 1, acc2[j].y);
    }
}

// ---------------- pass 2: LayerNorm in place on out ------------------------
__global__ __launch_bounds__(256) void caps_ln(
    const float* __restrict__ gamma,
    const float* __restrict__ beta,
    float* __restrict__ out)
{
    const size_t t = (size_t)blockIdx.x * 256 + threadIdx.x;  // 0..230399
    float* op = out + t * 16;

    float a[16];
#pragma unroll
    for (int j = 0; j < 16; j += 4) {
        float4 x = *(const float4*)(op + j);
        a[j] = x.x; a[j + 1] = x.y; a[j + 2] = x.z; a[j + 3] = x.w;
    }

    float mu = 0.0f;
#pragma unroll
    for (int j = 0; j < 16; ++j) mu += a[j];
    mu *= 0.0625f;
    float var = 0.0f;
#pragma unroll
    for (int j = 0; j < 16; ++j) { float d = a[j] - mu; var = fmaf(d, d, var); }
    var *= 0.0625f;
    float rstd = __builtin_amdgcn_rsqf(var + 1e-5f);

#pragma unroll
    for (int j = 0; j < 16; j += 4) {
        float4 g  = *(const float4*)(gamma + j);
        float4 be = *(const float4*)(beta + j);
        float4 r;
        r.x = (a[j + 0] - mu) * rstd * g.x + be.x;
        r.y = (a[j + 1] - mu) * rstd * g.y + be.y;
        r.z = (a[j + 2] - mu) * rstd * g.z + be.z;
        r.w = (a[j + 3] - mu) * rstd * g.w + be.w;
        *(float4*)(op + j) = r;
    }
}

extern "C" void kernel_launch(void* const* d_in, const int* in_sizes, int n_in,
                              void* d_out, int out_size, void* d_ws, size_t ws_size,
                              hipStream_t stream) {
    const float* input = (const float*)d_in[0];
    const float* ncv   = (const float*)d_in[1];
    const float* wt    = (const float*)d_in[2];
    const float* gamma = (const float*)d_in[3];
    const float* beta  = (const float*)d_in[4];
    float* out = (float*)d_out;
    float* wT  = (float*)d_ws;     // 147456 floats = 589 KB

    hipMemsetAsync(out, 0, (size_t)out_size * sizeof(float), stream);
    w_transpose<<<dim3(36), dim3(256), 0, stream>>>(wt, wT);
    caps_part<<<dim3(900, 2), dim3(256), 0, stream>>>(input, ncv, wT, out);
    caps_ln<<<dim3(900), dim3(256), 0, stream>>>(gamma, beta, out);
}

// Round 6
// 496.891 us; speedup vs baseline: 1.5337x; 1.5337x over previous
//
#include <hip/hip_runtime.h>

#define HOUT 15
#define WOUT 15
// input  (32, 32, 32, 32, 16)  fp32
// ncv    (32, 32, 15, 15, 16)  fp32
// w      (3, 3, 32, 4, 4, 32)  fp32   strides: kl 16384, n 512, xd 32, m 1
// out    (32, 32, 15, 15, 16)  fp32 = 3,686,400 floats

typedef float v2 __attribute__((ext_vector_type(2)));

// ---------------- pass 0: transpose w -> wT[n][kl][m][16] ------------------
// 9216 rows of 16 floats. Reads coalesced over m (stride-1), writes contiguous.
__global__ __launch_bounds__(256) void w_transpose(
    const float* __restrict__ wt, float* __restrict__ wT)
{
    const int t = blockIdx.x * 256 + threadIdx.x;   // 0..9215
    const int n  = t / 288;
    const int r  = t % 288;
    const int kl = r >> 5;
    const int m  = r & 31;

    const float* src = wt + kl * 16384 + n * 512 + m;
    float v[16];
#pragma unroll
    for (int xd = 0; xd < 16; ++xd) v[xd] = src[xd * 32];

    float* dst = wT + (size_t)t * 16;
#pragma unroll
    for (int j = 0; j < 4; ++j) {
        float4 o = {v[4 * j], v[4 * j + 1], v[4 * j + 2], v[4 * j + 3]};
        *(float4*)(dst + 4 * j) = o;
    }
}

// ---------------- pass 1: fully fused, no LDS / barriers / atomics ---------
// One 32-lane group per output position (b,h,w); lane = m. 4 groups per
// 128-thread block -> 1800 blocks. Full n=0..31 loop per group; LayerNorm
// epilogue entirely in registers; single coalesced float4 store.
// No launch_bounds VGPR cap: round 2/5 showed forcing occupancy causes
// spills / pathological allocation; natural ~110 VGPR -> 4 waves/SIMD.
__global__ void caps_fused(
    const float* __restrict__ input,
    const float* __restrict__ ncv,
    const float* __restrict__ wT,
    const float* __restrict__ gamma,
    const float* __restrict__ beta,
    float* __restrict__ out)
{
    const int tid  = threadIdx.x;
    const int grp  = tid >> 5;     // 0..3
    const int lane = tid & 31;     // m

    const int pos = blockIdx.x * 4 + grp;   // 0..7199
    const int b   = pos / (HOUT * WOUT);
    const int hw  = pos % (HOUT * WOUT);
    const int h   = hw / WOUT;
    const int wo  = hw % WOUT;

    // ncv[b, m=lane, h, wo, 0..15] packed as 8 x float2
    const float* ncv_p = ncv + ((((size_t)b * 32 + lane) * HOUT + h) * WOUT + wo) * 16;
    v2 cv2[8];
#pragma unroll
    for (int j = 0; j < 8; ++j) cv2[j] = *(const v2*)(ncv_p + j * 2);

    v2 acc2[8];
#pragma unroll
    for (int j = 0; j < 8; ++j) acc2[j] = (v2){0.0f, 0.0f};

    const int h0 = h * 2, w0 = wo * 2;

    for (int n = 0; n < 32; ++n) {
        const float* ipn = input + ((((size_t)b * 32 + n) * 32 + h0) * 32 + w0) * 16;
        const float* wn  = wT + ((size_t)n * 288 + lane) * 16;

#pragma unroll
        for (int k = 0; k < 3; ++k) {
#pragma unroll
            for (int l = 0; l < 3; ++l) {
                const int kl = k * 3 + l;
                // inp[b, n, 2h+k, 2w+l, 0..15] -- group-uniform broadcast
                const float* ip = ipn + (k * 32 + l) * 16;
                float av[16];
#pragma unroll
                for (int j = 0; j < 16; j += 4) {
                    float4 t = *(const float4*)(ip + j);
                    av[j] = t.x; av[j + 1] = t.y; av[j + 2] = t.z; av[j + 3] = t.w;
                }

                // wT row for (n,kl,m): 16 contiguous floats, lane-coalesced
                const float* wr = wn + kl * 512;   // 32 rows * 16 floats
                float4 wv[4];
#pragma unroll
                for (int x = 0; x < 4; ++x) wv[x] = *(const float4*)(wr + 4 * x);

                // u[a,d] = sum_x av[a,x]*w[x,d,m]; d-pairs -> v_pk_fma_f32
                v2 u2[8];
#pragma unroll
                for (int j = 0; j < 8; ++j) u2[j] = (v2){0.0f, 0.0f};
#pragma unroll
                for (int x = 0; x < 4; ++x) {
                    v2 wlo = {wv[x].x, wv[x].y};
                    v2 whi = {wv[x].z, wv[x].w};
#pragma unroll
                    for (int a = 0; a < 4; ++a) {
                        v2 sp = {av[a * 4 + x], av[a * 4 + x]};
                        u2[a * 2 + 0] = __builtin_elementwise_fma(sp, wlo, u2[a * 2 + 0]);
                        u2[a * 2 + 1] = __builtin_elementwise_fma(sp, whi, u2[a * 2 + 1]);
                    }
                }

                // logit = 0.25 * <u, cv>
                v2 d0 = {0.f, 0.f}, d1 = {0.f, 0.f};
#pragma unroll
                for (int j = 0; j < 4; ++j) {
                    d0 = __builtin_elementwise_fma(u2[j],     cv2[j],     d0);
                    d1 = __builtin_elementwise_fma(u2[j + 4], cv2[j + 4], d1);
                }
                v2 dd = d0 + d1;
                float logit = (dd.x + dd.y) * 0.25f;

                // softmax over m (32 lanes); no max-subtract (|logit| << 80)
                float e = __expf(logit);
                float sum = e;
#pragma unroll
                for (int o = 16; o > 0; o >>= 1)
                    sum += __shfl_xor(sum, o, 32);
                float p = e * __builtin_amdgcn_rcpf(sum);
                v2 p2 = {p, p};

#pragma unroll
                for (int j = 0; j < 8; ++j)
                    acc2[j] = __builtin_elementwise_fma(p2, u2[j], acc2[j]);
            }
        }
    }

    // LayerNorm over the 16 register-resident elements (per lane = per m)
    float a[16];
#pragma unroll
    for (int j = 0; j < 8; ++j) { a[2 * j] = acc2[j].x; a[2 * j + 1] = acc2[j].y; }

    float mu = 0.0f;
#pragma unroll
    for (int j = 0; j < 16; ++j) mu += a[j];
    mu *= 0.0625f;
    float var = 0.0f;
#pragma unroll
    for (int j = 0; j < 16; ++j) { float d = a[j] - mu; var = fmaf(d, d, var); }
    var *= 0.0625f;
    float rstd = __builtin_amdgcn_rsqf(var + 1e-5f);

    float* op = out + ((((size_t)b * 32 + lane) * HOUT + h) * WOUT + wo) * 16;
#pragma unroll
    for (int j = 0; j < 16; j += 4) {
        float4 g  = *(const float4*)(gamma + j);
        float4 be = *(const float4*)(beta + j);
        float4 r;
        r.x = (a[j + 0] - mu) * rstd * g.x + be.x;
        r.y = (a[j + 1] - mu) * rstd * g.y + be.y;
        r.z = (a[j + 2] - mu) * rstd * g.z + be.z;
        r.w = (a[j + 3] - mu) * rstd * g.w + be.w;
        *(float4*)(op + j) = r;
    }
}

extern "C" void kernel_launch(void* const* d_in, const int* in_sizes, int n_in,
                              void* d_out, int out_size, void* d_ws, size_t ws_size,
                              hipStream_t stream) {
    const float* input = (const float*)d_in[0];
    const float* ncv   = (const float*)d_in[1];
    const float* wt    = (const float*)d_in[2];
    const float* gamma = (const float*)d_in[3];
    const float* beta  = (const float*)d_in[4];
    float* out = (float*)d_out;
    float* wT  = (float*)d_ws;     // 147456 floats = 589 KB

    w_transpose<<<dim3(36), dim3(256), 0, stream>>>(wt, wT);
    caps_fused<<<dim3(1800), dim3(128), 0, stream>>>(input, ncv, wT, gamma, beta, out);
}

// Round 7
// 491.483 us; speedup vs baseline: 1.5506x; 1.0110x over previous
//
#include <hip/hip_runtime.h>

#define HOUT 15
#define WOUT 15
// input  (32, 32, 32, 32, 16)  fp32
// ncv    (32, 32, 15, 15, 16)  fp32
// w      (3, 3, 32, 4, 4, 32)  fp32   strides: kl 16384, n 512, xd 32, m 1
// out    (32, 32, 15, 15, 16)  fp32 = 3,686,400 floats

typedef float v2 __attribute__((ext_vector_type(2)));

// ---------------- pass 0: transpose w -> wT[n][kl][m][16] ------------------
__global__ __launch_bounds__(256) void w_transpose(
    const float* __restrict__ wt, float* __restrict__ wT)
{
    const int t = blockIdx.x * 256 + threadIdx.x;   // 0..9215
    const int n  = t / 288;
    const int r  = t % 288;
    const int kl = r >> 5;
    const int m  = r & 31;

    const float* src = wt + kl * 16384 + n * 512 + m;
    float v[16];
#pragma unroll
    for (int xd = 0; xd < 16; ++xd) v[xd] = src[xd * 32];

    float* dst = wT + (size_t)t * 16;
#pragma unroll
    for (int j = 0; j < 4; ++j) {
        float4 o = {v[4 * j], v[4 * j + 1], v[4 * j + 2], v[4 * j + 3]};
        *(float4*)(dst + 4 * j) = o;
    }
}

// ---------------- pass 1: fully fused, half-wave n-split -------------------
// One 64-lane WAVE per output position (b,h,w). lane&31 = m. Lanes 0..31
// process n=0..15, lanes 32..63 process n=16..31 (softmax is width-32, so it
// stays within each half). Partials combined by __shfl_xor(...,32) register
// adds -- no atomics, no partial buffers, no LDS, no barriers. 4 waves/block
// -> 1800 blocks = 7200 waves (2x round-6 parallelism).
// (256,2) pins the proven 112-VGPR no-spill regime (r2: (256,4) spills;
// r6: no bound -> 52 VGPR, ILP-starved).
__global__ __launch_bounds__(256, 2) void caps_fused(
    const float* __restrict__ input,
    const float* __restrict__ ncv,
    const float* __restrict__ wT,
    const float* __restrict__ gamma,
    const float* __restrict__ beta,
    float* __restrict__ out)
{
    const int tid  = threadIdx.x;
    const int grp  = tid >> 6;          // wave id 0..3 = position
    const int lane = tid & 31;          // m
    const int n0   = (tid & 32) >> 1;   // 0 | 16 : n-range of this half-wave

    const int pos = blockIdx.x * 4 + grp;   // 0..7199
    const int b   = pos / (HOUT * WOUT);
    const int hw  = pos % (HOUT * WOUT);
    const int h   = hw / WOUT;
    const int wo  = hw % WOUT;

    // ncv[b, m=lane, h, wo, 0..15] packed as 8 x float2 (same for both halves)
    const float* ncv_p = ncv + ((((size_t)b * 32 + lane) * HOUT + h) * WOUT + wo) * 16;
    v2 cv2[8];
#pragma unroll
    for (int j = 0; j < 8; ++j) cv2[j] = *(const v2*)(ncv_p + j * 2);

    v2 acc2[8];
#pragma unroll
    for (int j = 0; j < 8; ++j) acc2[j] = (v2){0.0f, 0.0f};

    const int h0 = h * 2, w0 = wo * 2;

    for (int i = 0; i < 16; ++i) {
        const int n = n0 + i;
        const float* ipn = input + ((((size_t)b * 32 + n) * 32 + h0) * 32 + w0) * 16;
        const float* wn  = wT + ((size_t)n * 288 + lane) * 16;

#pragma unroll
        for (int k = 0; k < 3; ++k) {
#pragma unroll
            for (int l = 0; l < 3; ++l) {
                const int kl = k * 3 + l;
                // inp[b, n, 2h+k, 2w+l, 0..15] -- uniform within each half
                const float* ip = ipn + (k * 32 + l) * 16;
                float av[16];
#pragma unroll
                for (int j = 0; j < 16; j += 4) {
                    float4 t = *(const float4*)(ip + j);
                    av[j] = t.x; av[j + 1] = t.y; av[j + 2] = t.z; av[j + 3] = t.w;
                }

                // wT row for (n,kl,m): 16 contiguous floats, lane-coalesced
                const float* wr = wn + kl * 512;
                float4 wv[4];
#pragma unroll
                for (int x = 0; x < 4; ++x) wv[x] = *(const float4*)(wr + 4 * x);

                // u[a,d] = sum_x av[a,x]*w[x,d,m]; d-pairs -> v_pk_fma_f32
                v2 u2[8];
#pragma unroll
                for (int j = 0; j < 8; ++j) u2[j] = (v2){0.0f, 0.0f};
#pragma unroll
                for (int x = 0; x < 4; ++x) {
                    v2 wlo = {wv[x].x, wv[x].y};
                    v2 whi = {wv[x].z, wv[x].w};
#pragma unroll
                    for (int a = 0; a < 4; ++a) {
                        v2 sp = {av[a * 4 + x], av[a * 4 + x]};
                        u2[a * 2 + 0] = __builtin_elementwise_fma(sp, wlo, u2[a * 2 + 0]);
                        u2[a * 2 + 1] = __builtin_elementwise_fma(sp, whi, u2[a * 2 + 1]);
                    }
                }

                // logit = 0.25 * <u, cv>
                v2 d0 = {0.f, 0.f}, d1 = {0.f, 0.f};
#pragma unroll
                for (int j = 0; j < 4; ++j) {
                    d0 = __builtin_elementwise_fma(u2[j],     cv2[j],     d0);
                    d1 = __builtin_elementwise_fma(u2[j + 4], cv2[j + 4], d1);
                }
                v2 dd = d0 + d1;
                float logit = (dd.x + dd.y) * 0.25f;

                // softmax over m (32 lanes, within this half-wave)
                float e = __expf(logit);
                float sum = e;
#pragma unroll
                for (int o = 16; o > 0; o >>= 1)
                    sum += __shfl_xor(sum, o, 32);
                float p = e * __builtin_amdgcn_rcpf(sum);
                v2 p2 = {p, p};

#pragma unroll
                for (int j = 0; j < 8; ++j)
                    acc2[j] = __builtin_elementwise_fma(p2, u2[j], acc2[j]);
            }
        }
    }

    // combine the two half-waves' partial sums (register-only)
#pragma unroll
    for (int j = 0; j < 8; ++j) {
        acc2[j].x += __shfl_xor(acc2[j].x, 32, 64);
        acc2[j].y += __shfl_xor(acc2[j].y, 32, 64);
    }

    // LayerNorm (computed redundantly in both halves; each stores 8 floats,
    // together one fully-contiguous 2 KB wave store)
    float a[16];
#pragma unroll
    for (int j = 0; j < 8; ++j) { a[2 * j] = acc2[j].x; a[2 * j + 1] = acc2[j].y; }

    float mu = 0.0f;
#pragma unroll
    for (int j = 0; j < 16; ++j) mu += a[j];
    mu *= 0.0625f;
    float var = 0.0f;
#pragma unroll
    for (int j = 0; j < 16; ++j) { float d = a[j] - mu; var = fmaf(d, d, var); }
    var *= 0.0625f;
    float rstd = __builtin_amdgcn_rsqf(var + 1e-5f);

    const int d8 = (tid & 32) >> 2;     // 0 | 8 : which 8 outputs this half stores
    float* op = out + ((((size_t)b * 32 + lane) * HOUT + h) * WOUT + wo) * 16 + d8;
#pragma unroll
    for (int j = 0; j < 8; j += 4) {
        float4 g  = *(const float4*)(gamma + d8 + j);
        float4 be = *(const float4*)(beta + d8 + j);
        float4 r;
        r.x = (a[d8 + j + 0] - mu) * rstd * g.x + be.x;
        r.y = (a[d8 + j + 1] - mu) * rstd * g.y + be.y;
        r.z = (a[d8 + j + 2] - mu) * rstd * g.z + be.z;
        r.w = (a[d8 + j + 3] - mu) * rstd * g.w + be.w;
        *(float4*)(op + j) = r;
    }
}

extern "C" void kernel_launch(void* const* d_in, const int* in_sizes, int n_in,
                              void* d_out, int out_size, void* d_ws, size_t ws_size,
                              hipStream_t stream) {
    const float* input = (const float*)d_in[0];
    const float* ncv   = (const float*)d_in[1];
    const float* wt    = (const float*)d_in[2];
    const float* gamma = (const float*)d_in[3];
    const float* beta  = (const float*)d_in[4];
    float* out = (float*)d_out;
    float* wT  = (float*)d_ws;     // 147456 floats = 589 KB

    w_transpose<<<dim3(36), dim3(256), 0, stream>>>(wt, wT);
    caps_fused<<<dim3(1800), dim3(256), 0, stream>>>(input, ncv, wT, gamma, beta, out);
}